// Round 1
// baseline (49438.516 us; speedup 1.0000x reference)
//
#include <hip/hip_runtime.h>
#include <hip/hip_bf16.h>

#define S_ 64
#define B_ 32
#define V_ 32000
#define E_ 512
#define H_ 1024
#define H3_ 3072

typedef __hip_bfloat16 bf16;
typedef __attribute__((ext_vector_type(8))) short s8v;
typedef __attribute__((ext_vector_type(4))) float f4;

__device__ __forceinline__ float b2f(bf16 x){ return __bfloat162float(x); }
__device__ __forceinline__ bf16  f2b(float x){ return __float2bfloat16(x); }
#define MFMA16(a,b,c) __builtin_amdgcn_mfma_f32_16x16x32_bf16((a),(b),(c),0,0,0)

// ---- device-scope grid barrier: slot-per-sync, bar[] zeroed by memset each launch ----
__device__ __forceinline__ void gbar(unsigned* bar, int slot, unsigned nblk){
  __syncthreads();
  if (threadIdx.x == 0){
    __threadfence();
    unsigned* p = bar + slot;
    atomicAdd(p, 1u);
    while (__hip_atomic_load(p, __ATOMIC_ACQUIRE, __HIP_MEMORY_SCOPE_AGENT) < nblk)
      __builtin_amdgcn_s_sleep(2);
  }
  __syncthreads();
}

// ---- prep kernels ----
__global__ __launch_bounds__(256) void cast_bf16_k(const float* __restrict__ s, bf16* __restrict__ d, int n){
  int i = blockIdx.x*256 + threadIdx.x;
  if (i < n) d[i] = f2b(s[i]);
}
__global__ __launch_bounds__(256) void gather_x_k(const float* __restrict__ emb, const int* __restrict__ seq, bf16* __restrict__ d){
  int i = blockIdx.x*256 + threadIdx.x;       // [0, 2048*512)
  int row = i >> 9, e = i & 511;
  d[i] = f2b(emb[(size_t)seq[row]*E_ + e]);
}
__global__ __launch_bounds__(256) void gather_lo_k(const float* __restrict__ emb, const int* __restrict__ tseq, const float* __restrict__ o0, bf16* __restrict__ d){
  int i = blockIdx.x*256 + threadIdx.x;
  int row = i >> 9, e = i & 511;
  int t = row >> 5, b = row & 31;
  float v = (t == 0) ? o0[e] : emb[(size_t)tseq[(t-1)*B_ + b]*E_ + e];
  d[i] = f2b(v);
}

// ---- generic bf16 MFMA GEMM: C[M,N] (+= / =) A[M,K] * B[N,K]^T (+bias) ----
// 128x128 tile, BK=32, 4 waves (2x2 of 64x64 wave-tiles, 4x4 of 16x16 frags)
template<int WB16, int ACC>
__global__ __launch_bounds__(256) void gemm_bt(const bf16* __restrict__ A, int lda,
                                               const bf16* __restrict__ B, int ldb,
                                               const float* __restrict__ bias,
                                               void* __restrict__ Cp, int ldc, int K)
{
  __shared__ bf16 a_sm[128][40];
  __shared__ bf16 b_sm[128][40];
  const int tid = threadIdx.x;
  const int m0 = blockIdx.y*128, n0 = blockIdx.x*128;
  const int w = tid>>6, l = tid&63;
  const int wm = w>>1, wn = w&1;
  f4 acc[4][4];
  #pragma unroll
  for (int i=0;i<4;i++)
    #pragma unroll
    for (int j=0;j<4;j++) acc[i][j] = (f4){0.f,0.f,0.f,0.f};
  const int srow = tid>>1, skc = (tid&1)*16;
  const int ar = l&15, koff = (l>>4)*8;
  for (int k0 = 0; k0 < K; k0 += 32){
    __syncthreads();
    const s8v* pa = (const s8v*)(A + (size_t)(m0+srow)*lda + k0 + skc);
    const s8v* pb = (const s8v*)(B + (size_t)(n0+srow)*ldb + k0 + skc);
    *(s8v*)&a_sm[srow][skc]   = pa[0];
    *(s8v*)&a_sm[srow][skc+8] = pa[1];
    *(s8v*)&b_sm[srow][skc]   = pb[0];
    *(s8v*)&b_sm[srow][skc+8] = pb[1];
    __syncthreads();
    s8v av[4], bv[4];
    #pragma unroll
    for (int i=0;i<4;i++) av[i] = *(const s8v*)&a_sm[wm*64 + i*16 + ar][koff];
    #pragma unroll
    for (int j=0;j<4;j++) bv[j] = *(const s8v*)&b_sm[wn*64 + j*16 + ar][koff];
    #pragma unroll
    for (int i=0;i<4;i++)
      #pragma unroll
      for (int j=0;j<4;j++)
        acc[i][j] = MFMA16(av[i], bv[j], acc[i][j]);
  }
  const int rb = (l>>4)*4;
  #pragma unroll
  for (int i=0;i<4;i++){
    #pragma unroll
    for (int j=0;j<4;j++){
      int col = n0 + wn*64 + j*16 + ar;
      float badd = bias ? bias[col] : 0.f;
      #pragma unroll
      for (int r=0;r<4;r++){
        int row = m0 + wm*64 + i*16 + rb + r;
        size_t idx = (size_t)row*ldc + col;
        float v = acc[i][j][r] + badd;
        if (ACC) v += ((const float*)Cp)[idx];
        if (WB16) ((bf16*)Cp)[idx] = f2b(v);
        else      ((float*)Cp)[idx] = v;
      }
    }
  }
}

// ---- bidirectional encoder GRU, persistent, 1 grid-sync per step ----
// h layout: [2 buf][2 dir][32][1024]
__global__ __launch_bounds__(256) void enc_loop_k(
  const float* __restrict__ gi_f, const float* __restrict__ gi_b,
  const bf16* __restrict__ whhf, const bf16* __restrict__ whhb,
  const float* __restrict__ bhhf, const float* __restrict__ bhhb,
  const float* __restrict__ enc_init,
  float* __restrict__ hf, bf16* __restrict__ hb,
  bf16* __restrict__ enc_out, unsigned* __restrict__ bar)
{
  const int tid = threadIdx.x, bid = blockIdx.x;
  const unsigned nblk = gridDim.x;
  {
    int tg = bid*256 + tid;                 // 65536 = buf0 exactly
    int dir = tg >> 15, col = tg & 1023;
    float v = enc_init[dir*H_ + col];
    hf[tg] = v; hb[tg] = f2b(v);
  }
  gbar(bar, 0, nblk);
  const int w = tid>>6, l = tid&63;
  const int lr = l&15, koff = (l>>4)*8, rb = (l>>4)*4;
  for (int s = 0; s < 64; ++s){
    if (w == 0){                            // 256 working waves spread 1/CU
      const int wid = bid;
      const int dir = wid>>7, rest = wid&127, mt = rest>>6, jt = rest&63;
      const int rbuf = s&1, wbuf = rbuf^1;
      const bf16*  hrd = hb + rbuf*65536 + dir*32768;
      const float* hfr = hf + rbuf*65536 + dir*32768;
      float* hfw = hf + wbuf*65536 + dir*32768;
      bf16*  hbw = hb + wbuf*65536 + dir*32768;
      const bf16* W   = dir ? whhb : whhf;
      const float* gi = dir ? gi_b : gi_f;
      const float* bhh= dir ? bhhb : bhhf;
      f4 accr = (f4){0,0,0,0}, accz = (f4){0,0,0,0}, accn = (f4){0,0,0,0};
      const int arow = mt*16 + lr, brow = jt*16 + lr;
      const bf16* pa = hrd + arow*H_ + koff;
      const bf16* pr = W + (size_t)brow*H_ + koff;
      const bf16* pz = W + (size_t)(H_ + brow)*H_ + koff;
      const bf16* pn = W + (size_t)(2*H_ + brow)*H_ + koff;
      #pragma unroll 4
      for (int k0 = 0; k0 < H_; k0 += 32){
        s8v a  = *(const s8v*)(pa + k0);
        s8v br = *(const s8v*)(pr + k0);
        s8v bz = *(const s8v*)(pz + k0);
        s8v bn = *(const s8v*)(pn + k0);
        accr = MFMA16(a, br, accr);
        accz = MFMA16(a, bz, accz);
        accn = MFMA16(a, bn, accn);
      }
      const int es = dir ? (63 - s) : s;
      const int col = jt*16 + lr;
      const float br_ = bhh[col], bz_ = bhh[H_+col], bn_ = bhh[2*H_+col];
      #pragma unroll
      for (int ri = 0; ri < 4; ++ri){
        const int b_ = mt*16 + rb + ri;
        const size_t gr = (size_t)(es*B_ + b_)*H3_;
        float ir = gi[gr + col], iz = gi[gr + H_ + col], inn = gi[gr + 2*H_ + col];
        float rg = 1.f/(1.f + expf(-(ir + accr[ri] + br_)));
        float zg = 1.f/(1.f + expf(-(iz + accz[ri] + bz_)));
        float ng = tanhf(inn + rg*(accn[ri] + bn_));
        float hold = hfr[b_*H_ + col];
        float hnew = (1.f - zg)*ng + zg*hold;
        hfw[b_*H_ + col] = hnew;
        hbw[b_*H_ + col] = f2b(hnew);
        enc_out[(size_t)(es*B_ + b_)*2048 + dir*H_ + col] = f2b(hnew);
      }
    }
    gbar(bar, 1+s, nblk);
  }
}

// ---- decoder with attention, persistent, 3 grid-syncs per step ----
__global__ __launch_bounds__(256) void dec_loop_k(
  const float* __restrict__ gi_base,   // [2048][3072] includes bih + tok/lastout parts
  const bf16* __restrict__ encW1b,     // [2048][1024]
  const bf16* __restrict__ encWgb,     // [2048][3072]
  const bf16* __restrict__ whhd,       // [3072][1024]
  const float* __restrict__ bhhd,
  const bf16* __restrict__ w1b,        // [1024][3072] full attn_W1 (h part = cols 2048..)
  const float* __restrict__ attnW2,    // [1024]
  const float* __restrict__ dinh,      // [1024]
  float* __restrict__ hdf, bf16* __restrict__ hdb,   // [32][1024]
  bf16* __restrict__ hW1b,             // [32][1024]
  float* __restrict__ gh,              // [32][3072] (includes bhh)
  float* __restrict__ wat,             // [64][32]
  bf16* __restrict__ h_all,            // [2048][1024]
  unsigned* __restrict__ bar)
{
  const int tid = threadIdx.x, bid = blockIdx.x;
  const unsigned nblk = gridDim.x;
  __shared__ float sc[32];
  {
    int tg = bid*256 + tid;
    if (tg < 32768){ float v = dinh[tg & 1023]; hdf[tg] = v; hdb[tg] = f2b(v); }
  }
  gbar(bar, 128, nblk);
  const int w = tid>>6, l = tid&63;
  const int lr = l&15, koff = (l>>4)*8, rbv = (l>>4)*4;
  int slot = 129;
  for (int t = 0; t < 64; ++t){
    // ---- phase A: hW1 = h @ W1h^T  (w==0, 128 blocks)  +  gh = h @ Whh^T (+bhh) (w==1,2)
    if (w == 0 && bid < 128){
      const int mt = bid>>6, jt = bid&63;
      f4 acc = (f4){0,0,0,0};
      const bf16* pa = hdb + (mt*16 + lr)*H_ + koff;
      const bf16* pb = w1b + (size_t)(jt*16 + lr)*H3_ + 2048 + koff;
      #pragma unroll 4
      for (int k0 = 0; k0 < H_; k0 += 32)
        acc = MFMA16(*(const s8v*)(pa + k0), *(const s8v*)(pb + k0), acc);
      const int col = jt*16 + lr;
      #pragma unroll
      for (int ri=0; ri<4; ++ri)
        hW1b[(mt*16 + rbv + ri)*H_ + col] = f2b(acc[ri]);
    } else if (w == 1 || w == 2){
      const int wid2 = (w-1)*256 + bid;
      if (wid2 < 384){
        const int mt = wid2/192, nt = wid2%192;
        f4 acc = (f4){0,0,0,0};
        const bf16* pa = hdb + (mt*16 + lr)*H_ + koff;
        const bf16* pb = whhd + (size_t)(nt*16 + lr)*H_ + koff;
        #pragma unroll 4
        for (int k0=0;k0<H_;k0+=32)
          acc = MFMA16(*(const s8v*)(pa+k0), *(const s8v*)(pb+k0), acc);
        const int col = nt*16 + lr;
        const float bv = bhhd[col];
        #pragma unroll
        for (int ri=0;ri<4;++ri)
          gh[(mt*16 + rbv + ri)*H3_ + col] = acc[ri] + bv;
      }
    }
    gbar(bar, slot++, nblk);
    // ---- phase B: scores + softmax over batch (block s, s<64)
    if (bid < 64){
      const int s = bid;
      const int b_ = tid>>3, part = tid&7;
      const bf16* e  = encW1b + (size_t)(s*B_ + b_)*H_ + part*128;
      const bf16* hw = hW1b + b_*H_ + part*128;
      const float* w2 = attnW2 + part*128;
      float p = 0.f;
      for (int i=0;i<128;++i)
        p += w2[i]*tanhf(b2f(e[i]) + b2f(hw[i]));
      p += __shfl_xor(p,1); p += __shfl_xor(p,2); p += __shfl_xor(p,4);
      if (part == 0) sc[b_] = p;
      __syncthreads();
      if (tid < 32){
        float ev = expf(sc[tid]);
        float ssum = ev;
        ssum += __shfl_xor(ssum,1);  ssum += __shfl_xor(ssum,2);
        ssum += __shfl_xor(ssum,4);  ssum += __shfl_xor(ssum,8);
        ssum += __shfl_xor(ssum,16);
        wat[s*B_ + tid] = ev/ssum;
      }
    }
    gbar(bar, slot++, nblk);
    // ---- phase D: glimpse-gates weighted sum + GRU pointwise
    if (tid < 128){
      const int tg = bid*128 + tid;            // 32768 = 32*1024
      const int b_ = tg>>10, j = tg&1023;
      float g0=0.f, g1=0.f, g2=0.f;
      for (int s2=0;s2<64;++s2){
        float wv = wat[s2*B_ + b_];
        size_t ro = (size_t)(s2*B_ + b_)*H3_;
        g0 += wv*b2f(encWgb[ro + j]);
        g1 += wv*b2f(encWgb[ro + H_ + j]);
        g2 += wv*b2f(encWgb[ro + 2*H_ + j]);
      }
      size_t gr = (size_t)(t*B_ + b_)*H3_;
      float ir  = gi_base[gr + j] + g0;
      float iz  = gi_base[gr + H_ + j] + g1;
      float inn = gi_base[gr + 2*H_ + j] + g2;
      float hr_ = gh[b_*H3_ + j], hz_ = gh[b_*H3_ + H_ + j], hn_ = gh[b_*H3_ + 2*H_ + j];
      float rg = 1.f/(1.f + expf(-(ir + hr_)));
      float zg = 1.f/(1.f + expf(-(iz + hz_)));
      float ng = tanhf(inn + rg*hn_);
      float hold = hdf[b_*H_ + j];
      float hnew = (1.f - zg)*ng + zg*hold;
      hdf[b_*H_ + j] = hnew;
      hdb[b_*H_ + j] = f2b(hnew);
      h_all[(size_t)(t*B_ + b_)*H_ + j] = f2b(hnew);
    }
    gbar(bar, slot++, nblk);
  }
}

// ---- row softmax over V (in place on d_out) ----
__global__ __launch_bounds__(256) void softmax_rows_k(float* __restrict__ out){
  __shared__ float wred[4];
  const int tid = threadIdx.x;
  float* p = out + (size_t)blockIdx.x*V_;
  float m = -1e30f;
  for (int j = tid; j < V_; j += 256) m = fmaxf(m, p[j]);
  #pragma unroll
  for (int o = 32; o; o >>= 1) m = fmaxf(m, __shfl_xor(m, o));
  if ((tid&63)==0) wred[tid>>6] = m;
  __syncthreads();
  m = fmaxf(fmaxf(wred[0],wred[1]), fmaxf(wred[2],wred[3]));
  __syncthreads();
  float s = 0.f;
  for (int j = tid; j < V_; j += 256) s += expf(p[j]-m);
  #pragma unroll
  for (int o = 32; o; o >>= 1) s += __shfl_xor(s, o);
  if ((tid&63)==0) wred[tid>>6] = s;
  __syncthreads();
  s = wred[0]+wred[1]+wred[2]+wred[3];
  float inv = 1.f/s;
  for (int j = tid; j < V_; j += 256) p[j] = expf(p[j]-m)*inv;
}

extern "C" void kernel_launch(void* const* d_in, const int* in_sizes, int n_in,
                              void* d_out, int out_size, void* d_ws, size_t ws_size,
                              hipStream_t stream)
{
  (void)in_sizes; (void)n_in; (void)out_size; (void)ws_size;
  const int*   iseq  = (const int*)d_in[0];
  const int*   tseq  = (const int*)d_in[1];
  const float* emb   = (const float*)d_in[2];
  const float* wihf  = (const float*)d_in[3];
  const float* bihf  = (const float*)d_in[5];
  const float* bhhf  = (const float*)d_in[6];
  const float* wihb  = (const float*)d_in[7];
  const float* bihb  = (const float*)d_in[9];
  const float* bhhb  = (const float*)d_in[10];
  const float* einit = (const float*)d_in[11];
  const float* wihd  = (const float*)d_in[12];
  const float* bihd  = (const float*)d_in[14];
  const float* bhhd  = (const float*)d_in[15];
  const float* dinh  = (const float*)d_in[16];
  const float* dino  = (const float*)d_in[17];
  const float* w1    = (const float*)d_in[18];
  const float* w2    = (const float*)d_in[19];
  const float* outw  = (const float*)d_in[20];
  const float* outb  = (const float*)d_in[21];
  const float* whhf_f = (const float*)d_in[4];
  const float* whhb_f = (const float*)d_in[8];
  const float* whhd_f = (const float*)d_in[13];
  float* out = (float*)d_out;

  char* ws = (char*)d_ws;
  size_t off = 0;
  auto alloc = [&](size_t bytes)->char*{ char* p = ws + off; off += (bytes + 255) & ~(size_t)255; return p; };
  unsigned* bar  = (unsigned*)alloc(2048);
  bf16* x_b      = (bf16*)alloc((size_t)2048*512*2);
  bf16* lo_b     = (bf16*)alloc((size_t)2048*512*2);
  bf16* wihf_b   = (bf16*)alloc((size_t)3072*512*2);
  bf16* wihb_b   = (bf16*)alloc((size_t)3072*512*2);
  bf16* whhf_b   = (bf16*)alloc((size_t)3072*1024*2);
  bf16* whhb_b   = (bf16*)alloc((size_t)3072*1024*2);
  bf16* wihd_b   = (bf16*)alloc((size_t)3072*3072*2);
  bf16* whhd_b   = (bf16*)alloc((size_t)3072*1024*2);
  bf16* w1_b     = (bf16*)alloc((size_t)1024*3072*2);
  bf16* outw_b   = (bf16*)alloc((size_t)32000*1024*2);
  float* gi_f    = (float*)alloc((size_t)2048*3072*4);
  float* gi_b    = (float*)alloc((size_t)2048*3072*4);
  float* gi_d    = (float*)alloc((size_t)2048*3072*4);
  bf16* enc_b    = (bf16*)alloc((size_t)2048*2048*2);
  bf16* encW1_b  = (bf16*)alloc((size_t)2048*1024*2);
  bf16* encWg_b  = (bf16*)alloc((size_t)2048*3072*2);
  float* henc_f  = (float*)alloc((size_t)2*65536*4);
  bf16*  henc_b  = (bf16*)alloc((size_t)2*65536*2);
  float* hdf     = (float*)alloc((size_t)32768*4);
  bf16*  hdb     = (bf16*)alloc((size_t)32768*2);
  bf16*  hW1b    = (bf16*)alloc((size_t)32768*2);
  float* ghb     = (float*)alloc((size_t)32*3072*4);
  float* wat     = (float*)alloc((size_t)64*32*4);
  bf16*  hall_b  = (bf16*)alloc((size_t)2048*1024*2);

  hipMemsetAsync(bar, 0, 2048, stream);

  gather_x_k <<<4096, 256, 0, stream>>>(emb, iseq, x_b);
  gather_lo_k<<<4096, 256, 0, stream>>>(emb, tseq, dino, lo_b);
  cast_bf16_k<<< 6144, 256, 0, stream>>>(wihf,   wihf_b, 3072*512);
  cast_bf16_k<<< 6144, 256, 0, stream>>>(wihb,   wihb_b, 3072*512);
  cast_bf16_k<<<12288, 256, 0, stream>>>(whhf_f, whhf_b, 3072*1024);
  cast_bf16_k<<<12288, 256, 0, stream>>>(whhb_f, whhb_b, 3072*1024);
  cast_bf16_k<<<36864, 256, 0, stream>>>(wihd,   wihd_b, 3072*3072);
  cast_bf16_k<<<12288, 256, 0, stream>>>(whhd_f, whhd_b, 3072*1024);
  cast_bf16_k<<<12288, 256, 0, stream>>>(w1,     w1_b,   1024*3072);
  cast_bf16_k<<<128000,256, 0, stream>>>(outw,   outw_b, 32000*1024);

  // batched gi precomputes
  gemm_bt<0,0><<<dim3(24,16), 256, 0, stream>>>(x_b, 512, wihf_b,      512,  bihf,    gi_f, 3072, 512);
  gemm_bt<0,0><<<dim3(24,16), 256, 0, stream>>>(x_b, 512, wihb_b,      512,  bihb,    gi_b, 3072, 512);
  gemm_bt<0,0><<<dim3(24,16), 256, 0, stream>>>(x_b, 512, wihd_b,      3072, bihd,    gi_d, 3072, 512);
  gemm_bt<0,1><<<dim3(24,16), 256, 0, stream>>>(lo_b,512, wihd_b+2560, 3072, nullptr, gi_d, 3072, 512);

  enc_loop_k<<<256, 256, 0, stream>>>(gi_f, gi_b, whhf_b, whhb_b, bhhf, bhhb, einit,
                                      henc_f, henc_b, enc_b, bar);

  // loop-invariant attention precomputes
  gemm_bt<1,0><<<dim3(8,16),  256, 0, stream>>>(enc_b, 2048, w1_b,       3072, nullptr, encW1_b, 1024, 2048);
  gemm_bt<1,0><<<dim3(24,16), 256, 0, stream>>>(enc_b, 2048, wihd_b+512, 3072, nullptr, encWg_b, 3072, 2048);

  dec_loop_k<<<256, 256, 0, stream>>>(gi_d, encW1_b, encWg_b, whhd_b, bhhd, w1_b, w2, dinh,
                                      hdf, hdb, hW1b, ghb, wat, hall_b, bar);

  // batched output projection + softmax
  gemm_bt<0,0><<<dim3(250,16), 256, 0, stream>>>(hall_b, 1024, outw_b, 1024, outb, out, 32000, 1024);
  softmax_rows_k<<<2048, 256, 0, stream>>>(out);
}

// Round 2
// 5034.885 us; speedup vs baseline: 9.8192x; 9.8192x over previous
//
#include <hip/hip_runtime.h>
#include <hip/hip_bf16.h>

#define S_ 64
#define B_ 32
#define V_ 32000
#define E_ 512
#define H_ 1024
#define H3_ 3072

typedef __hip_bfloat16 bf16;
typedef __attribute__((ext_vector_type(8))) short s8v;
typedef __attribute__((ext_vector_type(4))) float f4;

__device__ __forceinline__ float b2f(bf16 x){ return __bfloat162float(x); }
__device__ __forceinline__ bf16  f2b(float x){ return __float2bfloat16(x); }
__device__ __forceinline__ float bfu2f(unsigned short u){
  union { unsigned u; float f; } c; c.u = ((unsigned)u) << 16; return c.f;
}
#define MFMA16(a,b,c) __builtin_amdgcn_mfma_f32_16x16x32_bf16((a),(b),(c),0,0,0)

// fast tanh/sigmoid via hardware exp
__device__ __forceinline__ float fsigmoid(float x){ return 1.f/(1.f + __expf(-x)); }
__device__ __forceinline__ float ftanh(float x){ float e2 = __expf(2.f*x); return 1.f - 2.f/(e2 + 1.f); }

// ---- hierarchical grid barrier ----
// per-slot layout (uints): gcnt[g] at g*32 (g<16), root at 16*32, go[g] at (17+g)*32
// slot stride = 1056 uints = 4224 B. bar[] zeroed by hipMemsetAsync each launch.
// groups of 8 blocks; relaxed polls (no per-poll cache inv) + one threadfence after.
#define SLOT_U 1056
__device__ __forceinline__ void gbar(unsigned* bar, int slot, int bid, int ngrp){
  __syncthreads();
  if (threadIdx.x == 0){
    unsigned* base = bar + (size_t)slot*SLOT_U;
    const int g = bid >> 3;
    __threadfence();   // release: prior stores visible at LLC
    unsigned old = __hip_atomic_fetch_add(base + g*32, 1u, __ATOMIC_RELAXED, __HIP_MEMORY_SCOPE_AGENT);
    bool done = false;
    if (old == 7u){
      unsigned r = __hip_atomic_fetch_add(base + 16*32, 1u, __ATOMIC_RELAXED, __HIP_MEMORY_SCOPE_AGENT);
      if (r == (unsigned)(ngrp - 1)){
        #pragma unroll
        for (int gg = 0; gg < 16; ++gg){
          if (gg < ngrp)
            __hip_atomic_store(base + (17+gg)*32, 1u, __ATOMIC_RELAXED, __HIP_MEMORY_SCOPE_AGENT);
        }
        done = true;
      }
    }
    if (!done){
      while (__hip_atomic_load(base + (17+g)*32, __ATOMIC_RELAXED, __HIP_MEMORY_SCOPE_AGENT) == 0u)
        __builtin_amdgcn_s_sleep(2);
    }
    __threadfence();   // acquire: invalidate caches once
  }
  __syncthreads();
}

// ---- prep kernels (vectorized: 8 elems / thread) ----
__global__ __launch_bounds__(256) void cast_bf16_k(const float* __restrict__ s, bf16* __restrict__ d, int n8){
  int stride = gridDim.x*256;
  for (int i = blockIdx.x*256 + threadIdx.x; i < n8; i += stride){
    f4 a = *((const f4*)s + (size_t)i*2);
    f4 b = *((const f4*)s + (size_t)i*2 + 1);
    union { s8v v; bf16 h[8]; } o;
    #pragma unroll
    for (int k=0;k<4;k++){ o.h[k]=f2b(a[k]); o.h[4+k]=f2b(b[k]); }
    *((s8v*)d + i) = o.v;
  }
}
__global__ __launch_bounds__(256) void gather_x_k(const float* __restrict__ emb, const int* __restrict__ seq, bf16* __restrict__ d){
  int i = blockIdx.x*256 + threadIdx.x;     // [0, 2048*64)
  int row = i >> 6, e8 = i & 63;
  const float* src = emb + (size_t)seq[row]*E_;
  f4 a = *((const f4*)src + e8*2);
  f4 b = *((const f4*)src + e8*2 + 1);
  union { s8v v; bf16 h[8]; } o;
  #pragma unroll
  for (int k=0;k<4;k++){ o.h[k]=f2b(a[k]); o.h[4+k]=f2b(b[k]); }
  *((s8v*)d + i) = o.v;
}
__global__ __launch_bounds__(256) void gather_lo_k(const float* __restrict__ emb, const int* __restrict__ tseq, const float* __restrict__ o0, bf16* __restrict__ d){
  int i = blockIdx.x*256 + threadIdx.x;     // [0, 2048*64)
  int row = i >> 6, e8 = i & 63;
  int t = row >> 5, b = row & 31;
  const float* src = (t == 0) ? o0 : (emb + (size_t)tseq[(t-1)*B_ + b]*E_);
  f4 a = *((const f4*)src + e8*2);
  f4 c = *((const f4*)src + e8*2 + 1);
  union { s8v v; bf16 h[8]; } o;
  #pragma unroll
  for (int k=0;k<4;k++){ o.h[k]=f2b(a[k]); o.h[4+k]=f2b(c[k]); }
  *((s8v*)d + i) = o.v;
}

// ---- generic bf16 MFMA GEMM: C[M,N] (+= / =) A[M,K] * B[N,K]^T (+bias) ----
template<int WB16, int ACC>
__global__ __launch_bounds__(256) void gemm_bt(const bf16* __restrict__ A, int lda,
                                               const bf16* __restrict__ B, int ldb,
                                               const float* __restrict__ bias,
                                               void* __restrict__ Cp, int ldc, int K)
{
  __shared__ bf16 a_sm[128][40];
  __shared__ bf16 b_sm[128][40];
  const int tid = threadIdx.x;
  const int m0 = blockIdx.y*128, n0 = blockIdx.x*128;
  const int w = tid>>6, l = tid&63;
  const int wm = w>>1, wn = w&1;
  f4 acc[4][4];
  #pragma unroll
  for (int i=0;i<4;i++)
    #pragma unroll
    for (int j=0;j<4;j++) acc[i][j] = (f4){0.f,0.f,0.f,0.f};
  const int srow = tid>>1, skc = (tid&1)*16;
  const int ar = l&15, koff = (l>>4)*8;
  for (int k0 = 0; k0 < K; k0 += 32){
    __syncthreads();
    const s8v* pa = (const s8v*)(A + (size_t)(m0+srow)*lda + k0 + skc);
    const s8v* pb = (const s8v*)(B + (size_t)(n0+srow)*ldb + k0 + skc);
    *(s8v*)&a_sm[srow][skc]   = pa[0];
    *(s8v*)&a_sm[srow][skc+8] = pa[1];
    *(s8v*)&b_sm[srow][skc]   = pb[0];
    *(s8v*)&b_sm[srow][skc+8] = pb[1];
    __syncthreads();
    s8v av[4], bv[4];
    #pragma unroll
    for (int i=0;i<4;i++) av[i] = *(const s8v*)&a_sm[wm*64 + i*16 + ar][koff];
    #pragma unroll
    for (int j=0;j<4;j++) bv[j] = *(const s8v*)&b_sm[wn*64 + j*16 + ar][koff];
    #pragma unroll
    for (int i=0;i<4;i++)
      #pragma unroll
      for (int j=0;j<4;j++)
        acc[i][j] = MFMA16(av[i], bv[j], acc[i][j]);
  }
  const int rb = (l>>4)*4;
  #pragma unroll
  for (int i=0;i<4;i++){
    #pragma unroll
    for (int j=0;j<4;j++){
      int col = n0 + wn*64 + j*16 + ar;
      float badd = bias ? bias[col] : 0.f;
      #pragma unroll
      for (int r=0;r<4;r++){
        int row = m0 + wm*64 + i*16 + rb + r;
        size_t idx = (size_t)row*ldc + col;
        float v = acc[i][j][r] + badd;
        if (ACC) v += ((const float*)Cp)[idx];
        if (WB16) ((bf16*)Cp)[idx] = f2b(v);
        else      ((float*)Cp)[idx] = v;
      }
    }
  }
}

// ---- bidirectional encoder GRU: 64 blocks x 4 waves (1 wave-task each), 1 sync/step ----
// hb: [2 buf][2 dir][32][1024] bf16; fp32 h master lives in registers (static task map)
__global__ __launch_bounds__(256) void enc_loop_k(
  const float* __restrict__ gi_f, const float* __restrict__ gi_b,
  const bf16* __restrict__ whhf, const bf16* __restrict__ whhb,
  const float* __restrict__ bhhf, const float* __restrict__ bhhb,
  const float* __restrict__ enc_init,
  bf16* __restrict__ hb, bf16* __restrict__ enc_out, unsigned* __restrict__ bar)
{
  const int tid = threadIdx.x, bid = blockIdx.x;
  const int w = tid>>6, l = tid&63;
  const int lr = l&15, koff = (l>>4)*8, rb = (l>>4)*4;
  const int wid = bid*4 + w;                 // 0..255
  const int dir = wid>>7, rest = wid&127, mt = rest>>6, jt = rest&63;
  const int col = jt*16 + lr;
  const bf16* W    = dir ? whhb : whhf;
  const float* gi  = dir ? gi_b : gi_f;
  const float* bhh = dir ? bhhb : bhhf;
  const float br_ = bhh[col], bz_ = bhh[H_+col], bn_ = bhh[2*H_+col];
  float hreg[4];
  {
    float v = enc_init[dir*H_ + col];
    bf16 vb = f2b(v);
    #pragma unroll
    for (int ri=0; ri<4; ++ri){
      hreg[ri] = v;
      hb[dir*32768 + (mt*16 + rb + ri)*H_ + col] = vb;   // buf 0
    }
  }
  gbar(bar, 0, bid, 8);
  for (int s = 0; s < 64; ++s){
    const int rbuf = s&1, wbuf = rbuf^1;
    const bf16* hrd = hb + rbuf*65536 + dir*32768;
    bf16*      hbw  = hb + wbuf*65536 + dir*32768;
    f4 accr = (f4){0,0,0,0}, accz = (f4){0,0,0,0}, accn = (f4){0,0,0,0};
    const bf16* pa = hrd + (mt*16 + lr)*H_ + koff;
    const bf16* pr = W + (size_t)(jt*16 + lr)*H_ + koff;
    const bf16* pz = pr + (size_t)H_*H_;
    const bf16* pn = pz + (size_t)H_*H_;
    #pragma unroll 4
    for (int k0 = 0; k0 < H_; k0 += 32){
      s8v a = *(const s8v*)(pa + k0);
      accr = MFMA16(a, *(const s8v*)(pr + k0), accr);
      accz = MFMA16(a, *(const s8v*)(pz + k0), accz);
      accn = MFMA16(a, *(const s8v*)(pn + k0), accn);
    }
    const int es = dir ? (63 - s) : s;
    #pragma unroll
    for (int ri = 0; ri < 4; ++ri){
      const int b_ = mt*16 + rb + ri;
      const size_t gr = (size_t)(es*B_ + b_)*H3_;
      float ir = gi[gr + col], iz = gi[gr + H_ + col], inn = gi[gr + 2*H_ + col];
      float rg = fsigmoid(ir + accr[ri] + br_);
      float zg = fsigmoid(iz + accz[ri] + bz_);
      float ng = ftanh(inn + rg*(accn[ri] + bn_));
      float hnew = (1.f - zg)*ng + zg*hreg[ri];
      hreg[ri] = hnew;
      bf16 h16 = f2b(hnew);
      hbw[b_*H_ + col] = h16;
      enc_out[(size_t)(es*B_ + b_)*2048 + dir*H_ + col] = h16;
    }
    gbar(bar, 1+s, bid, 8);
  }
}

// ---- decoder with attention: 128 blocks, 3 syncs/step ----
__global__ __launch_bounds__(256) void dec_loop_k(
  const float* __restrict__ gi_base,   // [2048][3072] (bih + tok/lastout parts)
  const bf16* __restrict__ encW1b,     // [2048][1024]
  const bf16* __restrict__ encWgb,     // [2048][3072]
  const bf16* __restrict__ whhd,       // [3072][1024]
  const float* __restrict__ bhhd,
  const bf16* __restrict__ w1b,        // [1024][3072] (h part = cols 2048..)
  const float* __restrict__ attnW2,    // [1024]
  const float* __restrict__ dinh,      // [1024]
  bf16* __restrict__ hdb,              // [32][1024]
  bf16* __restrict__ hW1b,             // [32][1024]
  float* __restrict__ gh,              // [32][3072]
  float* __restrict__ wat,             // [64][32]
  bf16* __restrict__ h_all,            // [2048][1024]
  unsigned* __restrict__ bar)
{
  const int tid = threadIdx.x, bid = blockIdx.x;
  __shared__ float sc[32];
  const int tg = bid*256 + tid;        // 0..32767 == (b, j)
  const int db = tg>>10, dj = tg&1023;
  float hreg = dinh[dj];
  hdb[tg] = f2b(hreg);
  gbar(bar, 80, bid, 16);
  const int w = tid>>6, l = tid&63;
  const int lr = l&15, koff = (l>>4)*8, rbv = (l>>4)*4;
  int slot = 81;
  for (int t = 0; t < 64; ++t){
    // ---- phase A: hW1 = h @ W1h^T (wave 0), gh = h @ Whh^T + bhh (waves 1-3)
    if (w == 0){
      const int mt = bid>>6, jt = bid&63;
      f4 acc = (f4){0,0,0,0};
      const bf16* pa = hdb + (mt*16 + lr)*H_ + koff;
      const bf16* pb = w1b + (size_t)(jt*16 + lr)*H3_ + 2048 + koff;
      #pragma unroll 4
      for (int k0 = 0; k0 < H_; k0 += 32)
        acc = MFMA16(*(const s8v*)(pa + k0), *(const s8v*)(pb + k0), acc);
      const int colA = jt*16 + lr;
      #pragma unroll
      for (int ri=0; ri<4; ++ri)
        hW1b[(mt*16 + rbv + ri)*H_ + colA] = f2b(acc[ri]);
    } else {
      const int wid2 = (w-1)*128 + bid;          // 0..383
      const int mt = wid2/192, nt = wid2%192;
      f4 acc = (f4){0,0,0,0};
      const bf16* pa = hdb + (mt*16 + lr)*H_ + koff;
      const bf16* pb = whhd + (size_t)(nt*16 + lr)*H_ + koff;
      #pragma unroll 4
      for (int k0=0;k0<H_;k0+=32)
        acc = MFMA16(*(const s8v*)(pa+k0), *(const s8v*)(pb+k0), acc);
      const int colA = nt*16 + lr;
      const float bv = bhhd[colA];
      #pragma unroll
      for (int ri=0;ri<4;++ri)
        gh[(mt*16 + rbv + ri)*H3_ + colA] = acc[ri] + bv;
    }
    gbar(bar, slot++, bid, 16);
    // ---- phase B: scores + softmax over batch (block s < 64)
    if (bid < 64){
      const int s = bid;
      const int b_ = tid>>3, part = tid&7;
      const bf16* e  = encW1b + (size_t)(s*B_ + b_)*H_ + part*128;
      const bf16* hw = hW1b + b_*H_ + part*128;
      const float* w2p = attnW2 + part*128;
      float p = 0.f;
      #pragma unroll 2
      for (int ii=0; ii<16; ++ii){
        union { s8v v; unsigned short u[8]; } ev, hv;
        ev.v = *(const s8v*)(e + ii*8);
        hv.v = *(const s8v*)(hw + ii*8);
        f4 wa  = *(const f4*)(w2p + ii*8);
        f4 wb2 = *(const f4*)(w2p + ii*8 + 4);
        #pragma unroll
        for (int k=0;k<8;k++){
          float x = bfu2f(ev.u[k]) + bfu2f(hv.u[k]);
          float th = ftanh(x);
          p += (k<4 ? wa[k] : wb2[k-4])*th;
        }
      }
      p += __shfl_xor(p,1); p += __shfl_xor(p,2); p += __shfl_xor(p,4);
      if (part == 0) sc[b_] = p;
      __syncthreads();
      if (tid < 32){
        float evx = __expf(sc[tid]);
        float ssum = evx;
        ssum += __shfl_xor(ssum,1);  ssum += __shfl_xor(ssum,2);
        ssum += __shfl_xor(ssum,4);  ssum += __shfl_xor(ssum,8);
        ssum += __shfl_xor(ssum,16);
        wat[s*B_ + tid] = evx/ssum;
      }
    }
    gbar(bar, slot++, bid, 16);
    // ---- phase D: glimpse weighted sum + GRU pointwise (one thread per (b,j))
    {
      float g0=0.f, g1=0.f, g2=0.f;
      #pragma unroll 4
      for (int s2=0;s2<64;++s2){
        float wv = wat[s2*B_ + db];
        const bf16* ro = encWgb + (size_t)(s2*B_ + db)*H3_ + dj;
        g0 += wv*b2f(ro[0]);
        g1 += wv*b2f(ro[H_]);
        g2 += wv*b2f(ro[2*H_]);
      }
      const size_t gr = (size_t)(t*B_ + db)*H3_;
      float ir  = gi_base[gr + dj] + g0;
      float iz  = gi_base[gr + H_ + dj] + g1;
      float inn = gi_base[gr + 2*H_ + dj] + g2;
      float hr_ = gh[db*H3_ + dj], hz_ = gh[db*H3_ + H_ + dj], hn_ = gh[db*H3_ + 2*H_ + dj];
      float rg = fsigmoid(ir + hr_);
      float zg = fsigmoid(iz + hz_);
      float ng = ftanh(inn + rg*hn_);
      float hnew = (1.f - zg)*ng + zg*hreg;
      hreg = hnew;
      bf16 h16 = f2b(hnew);
      hdb[db*H_ + dj] = h16;
      h_all[(size_t)(t*B_ + db)*H_ + dj] = h16;
    }
    gbar(bar, slot++, bid, 16);
  }
}

// ---- 2-pass online row softmax over V (in place on d_out) ----
__global__ __launch_bounds__(256) void softmax_rows_k(float* __restrict__ out){
  __shared__ float wm[4], wl[4];
  const int tid = threadIdx.x;
  float* p = out + (size_t)blockIdx.x*V_;
  float m = -1e30f, lsum = 0.f;
  for (int j = tid; j < V_; j += 256){
    float v = p[j];
    float mn = fmaxf(m, v);
    lsum = lsum*__expf(m - mn) + __expf(v - mn);
    m = mn;
  }
  #pragma unroll
  for (int o = 32; o; o >>= 1){
    float mo = __shfl_xor(m, o), lo_ = __shfl_xor(lsum, o);
    float mn = fmaxf(m, mo);
    lsum = lsum*__expf(m - mn) + lo_*__expf(mo - mn);
    m = mn;
  }
  if ((tid&63)==0){ wm[tid>>6] = m; wl[tid>>6] = lsum; }
  __syncthreads();
  float M = fmaxf(fmaxf(wm[0],wm[1]), fmaxf(wm[2],wm[3]));
  float L = wl[0]*__expf(wm[0]-M) + wl[1]*__expf(wm[1]-M)
          + wl[2]*__expf(wm[2]-M) + wl[3]*__expf(wm[3]-M);
  float inv = 1.f/L;
  for (int j = tid; j < V_; j += 256) p[j] = __expf(p[j]-M)*inv;
}

extern "C" void kernel_launch(void* const* d_in, const int* in_sizes, int n_in,
                              void* d_out, int out_size, void* d_ws, size_t ws_size,
                              hipStream_t stream)
{
  (void)in_sizes; (void)n_in; (void)out_size; (void)ws_size;
  const int*   iseq  = (const int*)d_in[0];
  const int*   tseq  = (const int*)d_in[1];
  const float* emb   = (const float*)d_in[2];
  const float* wihf  = (const float*)d_in[3];
  const float* whhf_f= (const float*)d_in[4];
  const float* bihf  = (const float*)d_in[5];
  const float* bhhf  = (const float*)d_in[6];
  const float* wihb  = (const float*)d_in[7];
  const float* whhb_f= (const float*)d_in[8];
  const float* bihb  = (const float*)d_in[9];
  const float* bhhb  = (const float*)d_in[10];
  const float* einit = (const float*)d_in[11];
  const float* wihd  = (const float*)d_in[12];
  const float* whhd_f= (const float*)d_in[13];
  const float* bihd  = (const float*)d_in[14];
  const float* bhhd  = (const float*)d_in[15];
  const float* dinh  = (const float*)d_in[16];
  const float* dino  = (const float*)d_in[17];
  const float* w1    = (const float*)d_in[18];
  const float* w2    = (const float*)d_in[19];
  const float* outw  = (const float*)d_in[20];
  const float* outb  = (const float*)d_in[21];
  float* out = (float*)d_out;

  char* ws = (char*)d_ws;
  size_t off = 0;
  auto alloc = [&](size_t bytes)->char*{ char* p = ws + off; off += (bytes + 255) & ~(size_t)255; return p; };
  const size_t bar_bytes = (size_t)273*SLOT_U*4;
  unsigned* bar  = (unsigned*)alloc(bar_bytes);
  bf16* x_b      = (bf16*)alloc((size_t)2048*512*2);
  bf16* lo_b     = (bf16*)alloc((size_t)2048*512*2);
  bf16* wihf_b   = (bf16*)alloc((size_t)3072*512*2);
  bf16* wihb_b   = (bf16*)alloc((size_t)3072*512*2);
  bf16* whhf_b   = (bf16*)alloc((size_t)3072*1024*2);
  bf16* whhb_b   = (bf16*)alloc((size_t)3072*1024*2);
  bf16* wihd_b   = (bf16*)alloc((size_t)3072*3072*2);
  bf16* whhd_b   = (bf16*)alloc((size_t)3072*1024*2);
  bf16* w1_b     = (bf16*)alloc((size_t)1024*3072*2);
  bf16* outw_b   = (bf16*)alloc((size_t)32000*1024*2);
  float* gi_f    = (float*)alloc((size_t)2048*3072*4);
  float* gi_b    = (float*)alloc((size_t)2048*3072*4);
  float* gi_d    = (float*)alloc((size_t)2048*3072*4);
  bf16* enc_b    = (bf16*)alloc((size_t)2048*2048*2);
  bf16* encW1_b  = (bf16*)alloc((size_t)2048*1024*2);
  bf16* encWg_b  = (bf16*)alloc((size_t)2048*3072*2);
  bf16*  henc_b  = (bf16*)alloc((size_t)2*65536*2);
  bf16*  hdb     = (bf16*)alloc((size_t)32768*2);
  bf16*  hW1b    = (bf16*)alloc((size_t)32768*2);
  float* ghb     = (float*)alloc((size_t)32*3072*4);
  float* wat     = (float*)alloc((size_t)64*32*4);
  bf16*  hall_b  = (bf16*)alloc((size_t)2048*1024*2);

  hipMemsetAsync(bar, 0, bar_bytes, stream);

  auto cgrid = [](int n8){ int g = (n8 + 255)/256; return g > 2048 ? 2048 : g; };
  gather_x_k <<<512, 256, 0, stream>>>(emb, iseq, x_b);
  gather_lo_k<<<512, 256, 0, stream>>>(emb, tseq, dino, lo_b);
  cast_bf16_k<<<cgrid(196608),  256, 0, stream>>>(wihf,   wihf_b, 196608);
  cast_bf16_k<<<cgrid(196608),  256, 0, stream>>>(wihb,   wihb_b, 196608);
  cast_bf16_k<<<cgrid(393216),  256, 0, stream>>>(whhf_f, whhf_b, 393216);
  cast_bf16_k<<<cgrid(393216),  256, 0, stream>>>(whhb_f, whhb_b, 393216);
  cast_bf16_k<<<cgrid(1179648), 256, 0, stream>>>(wihd,   wihd_b, 1179648);
  cast_bf16_k<<<cgrid(393216),  256, 0, stream>>>(whhd_f, whhd_b, 393216);
  cast_bf16_k<<<cgrid(393216),  256, 0, stream>>>(w1,     w1_b,   393216);
  cast_bf16_k<<<cgrid(4096000), 256, 0, stream>>>(outw,   outw_b, 4096000);

  // batched gi precomputes
  gemm_bt<0,0><<<dim3(24,16), 256, 0, stream>>>(x_b, 512, wihf_b,      512,  bihf,    gi_f, 3072, 512);
  gemm_bt<0,0><<<dim3(24,16), 256, 0, stream>>>(x_b, 512, wihb_b,      512,  bihb,    gi_b, 3072, 512);
  gemm_bt<0,0><<<dim3(24,16), 256, 0, stream>>>(x_b, 512, wihd_b,      3072, bihd,    gi_d, 3072, 512);
  gemm_bt<0,1><<<dim3(24,16), 256, 0, stream>>>(lo_b,512, wihd_b+2560, 3072, nullptr, gi_d, 3072, 512);

  enc_loop_k<<<64, 256, 0, stream>>>(gi_f, gi_b, whhf_b, whhb_b, bhhf, bhhb, einit,
                                     henc_b, enc_b, bar);

  // loop-invariant attention precomputes
  gemm_bt<1,0><<<dim3(8,16),  256, 0, stream>>>(enc_b, 2048, w1_b,       3072, nullptr, encW1_b, 1024, 2048);
  gemm_bt<1,0><<<dim3(24,16), 256, 0, stream>>>(enc_b, 2048, wihd_b+512, 3072, nullptr, encWg_b, 3072, 2048);

  dec_loop_k<<<128, 256, 0, stream>>>(gi_d, encW1_b, encWg_b, whhd_b, bhhd, w1_b, w2, dinh,
                                      hdb, hW1b, ghb, wat, hall_b, bar);

  // batched output projection + softmax
  gemm_bt<0,0><<<dim3(250,16), 256, 0, stream>>>(hall_b, 1024, outw_b, 1024, outb, out, 32000, 1024);
  softmax_rows_k<<<2048, 256, 0, stream>>>(out);
}

// Round 3
// 4720.757 us; speedup vs baseline: 10.4726x; 1.0665x over previous
//
#include <hip/hip_runtime.h>
#include <hip/hip_bf16.h>

#define S_ 64
#define B_ 32
#define V_ 32000
#define E_ 512
#define H_ 1024
#define H3_ 3072

typedef __hip_bfloat16 bf16;
typedef __attribute__((ext_vector_type(8))) short s8v;
typedef __attribute__((ext_vector_type(4))) float f4;

__device__ __forceinline__ float b2f(bf16 x){ return __bfloat162float(x); }
__device__ __forceinline__ bf16  f2b(float x){ return __float2bfloat16(x); }
__device__ __forceinline__ float bfu2f(unsigned short u){
  union { unsigned u; float f; } c; c.u = ((unsigned)u) << 16; return c.f;
}
#define MFMA16(a,b,c) __builtin_amdgcn_mfma_f32_16x16x32_bf16((a),(b),(c),0,0,0)

__device__ __forceinline__ float fsigmoid(float x){ return 1.f/(1.f + __expf(-x)); }
__device__ __forceinline__ float ftanh(float x){ float e2 = __expf(2.f*x); return 1.f - 2.f/(e2 + 1.f); }

// ---- device-scope (LLC-coherent, L1/L2-bypassing) accessors ----
__device__ __forceinline__ unsigned long long dld64(const void* p){
  return __hip_atomic_load((const unsigned long long*)p, __ATOMIC_RELAXED, __HIP_MEMORY_SCOPE_AGENT);
}
__device__ __forceinline__ float dldf(const void* p){
  unsigned u = __hip_atomic_load((const unsigned*)p, __ATOMIC_RELAXED, __HIP_MEMORY_SCOPE_AGENT);
  union{unsigned u; float f;} c; c.u=u; return c.f;
}
__device__ __forceinline__ void dstf(void* p, float v){
  union{float f; unsigned u;} c; c.f=v;
  __hip_atomic_store((unsigned*)p, c.u, __ATOMIC_RELAXED, __HIP_MEMORY_SCOPE_AGENT);
}
__device__ __forceinline__ void dsth(void* p, bf16 v){
  union{bf16 h; unsigned short u;} c; c.h=v;
  __hip_atomic_store((unsigned short*)p, c.u, __ATOMIC_RELAXED, __HIP_MEMORY_SCOPE_AGENT);
}

// ---- hierarchical grid barrier, NO cache fences (data goes device-scope) ----
// per-slot layout (uints): gcnt[g] at g*32 (g<16), root at 16*32, go[g] at (17+g)*32
#define SLOT_U 1056
__device__ __forceinline__ void gbar(unsigned* bar, int slot, int bid, int ngrp){
  __syncthreads();   // compiler drains vmcnt before s_barrier -> device stores at LLC
  if (threadIdx.x == 0){
    unsigned* base = bar + (size_t)slot*SLOT_U;
    const int g = bid >> 3;
    unsigned old = __hip_atomic_fetch_add(base + g*32, 1u, __ATOMIC_RELAXED, __HIP_MEMORY_SCOPE_AGENT);
    bool done = false;
    if (old == 7u){
      unsigned r = __hip_atomic_fetch_add(base + 16*32, 1u, __ATOMIC_RELAXED, __HIP_MEMORY_SCOPE_AGENT);
      if (r == (unsigned)(ngrp - 1)){
        #pragma unroll
        for (int gg = 0; gg < 16; ++gg){
          if (gg < ngrp)
            __hip_atomic_store(base + (17+gg)*32, 1u, __ATOMIC_RELAXED, __HIP_MEMORY_SCOPE_AGENT);
        }
        done = true;
      }
    }
    if (!done){
      while (__hip_atomic_load(base + (17+g)*32, __ATOMIC_RELAXED, __HIP_MEMORY_SCOPE_AGENT) == 0u)
        __builtin_amdgcn_s_sleep(2);
    }
  }
  __syncthreads();
  asm volatile("" ::: "memory");
}

// ---- prep kernels (vectorized: 8 elems / thread) ----
__global__ __launch_bounds__(256) void cast_bf16_k(const float* __restrict__ s, bf16* __restrict__ d, int n8){
  int stride = gridDim.x*256;
  for (int i = blockIdx.x*256 + threadIdx.x; i < n8; i += stride){
    f4 a = *((const f4*)s + (size_t)i*2);
    f4 b = *((const f4*)s + (size_t)i*2 + 1);
    union { s8v v; bf16 h[8]; } o;
    #pragma unroll
    for (int k=0;k<4;k++){ o.h[k]=f2b(a[k]); o.h[4+k]=f2b(b[k]); }
    *((s8v*)d + i) = o.v;
  }
}
__global__ __launch_bounds__(256) void gather_x_k(const float* __restrict__ emb, const int* __restrict__ seq, bf16* __restrict__ d){
  int i = blockIdx.x*256 + threadIdx.x;     // [0, 2048*64)
  int row = i >> 6, e8 = i & 63;
  const float* src = emb + (size_t)seq[row]*E_;
  f4 a = *((const f4*)src + e8*2);
  f4 b = *((const f4*)src + e8*2 + 1);
  union { s8v v; bf16 h[8]; } o;
  #pragma unroll
  for (int k=0;k<4;k++){ o.h[k]=f2b(a[k]); o.h[4+k]=f2b(b[k]); }
  *((s8v*)d + i) = o.v;
}
__global__ __launch_bounds__(256) void gather_lo_k(const float* __restrict__ emb, const int* __restrict__ tseq, const float* __restrict__ o0, bf16* __restrict__ d){
  int i = blockIdx.x*256 + threadIdx.x;     // [0, 2048*64)
  int row = i >> 6, e8 = i & 63;
  int t = row >> 5, b = row & 31;
  const float* src = (t == 0) ? o0 : (emb + (size_t)tseq[(t-1)*B_ + b]*E_);
  f4 a = *((const f4*)src + e8*2);
  f4 c = *((const f4*)src + e8*2 + 1);
  union { s8v v; bf16 h[8]; } o;
  #pragma unroll
  for (int k=0;k<4;k++){ o.h[k]=f2b(a[k]); o.h[4+k]=f2b(c[k]); }
  *((s8v*)d + i) = o.v;
}

// ---- generic bf16 MFMA GEMM: C[M,N] (+= / =) A[M,K] * B[N,K]^T (+bias) ----
template<int WB16, int ACC>
__global__ __launch_bounds__(256) void gemm_bt(const bf16* __restrict__ A, int lda,
                                               const bf16* __restrict__ B, int ldb,
                                               const float* __restrict__ bias,
                                               void* __restrict__ Cp, int ldc, int K)
{
  __shared__ bf16 a_sm[128][40];
  __shared__ bf16 b_sm[128][40];
  const int tid = threadIdx.x;
  const int m0 = blockIdx.y*128, n0 = blockIdx.x*128;
  const int w = tid>>6, l = tid&63;
  const int wm = w>>1, wn = w&1;
  f4 acc[4][4];
  #pragma unroll
  for (int i=0;i<4;i++)
    #pragma unroll
    for (int j=0;j<4;j++) acc[i][j] = (f4){0.f,0.f,0.f,0.f};
  const int srow = tid>>1, skc = (tid&1)*16;
  const int ar = l&15, koff = (l>>4)*8;
  for (int k0 = 0; k0 < K; k0 += 32){
    __syncthreads();
    const s8v* pa = (const s8v*)(A + (size_t)(m0+srow)*lda + k0 + skc);
    const s8v* pb = (const s8v*)(B + (size_t)(n0+srow)*ldb + k0 + skc);
    *(s8v*)&a_sm[srow][skc]   = pa[0];
    *(s8v*)&a_sm[srow][skc+8] = pa[1];
    *(s8v*)&b_sm[srow][skc]   = pb[0];
    *(s8v*)&b_sm[srow][skc+8] = pb[1];
    __syncthreads();
    s8v av[4], bv[4];
    #pragma unroll
    for (int i=0;i<4;i++) av[i] = *(const s8v*)&a_sm[wm*64 + i*16 + ar][koff];
    #pragma unroll
    for (int j=0;j<4;j++) bv[j] = *(const s8v*)&b_sm[wn*64 + j*16 + ar][koff];
    #pragma unroll
    for (int i=0;i<4;i++)
      #pragma unroll
      for (int j=0;j<4;j++)
        acc[i][j] = MFMA16(av[i], bv[j], acc[i][j]);
  }
  const int rb = (l>>4)*4;
  #pragma unroll
  for (int i=0;i<4;i++){
    #pragma unroll
    for (int j=0;j<4;j++){
      int col = n0 + wn*64 + j*16 + ar;
      float badd = bias ? bias[col] : 0.f;
      #pragma unroll
      for (int r=0;r<4;r++){
        int row = m0 + wm*64 + i*16 + rb + r;
        size_t idx = (size_t)row*ldc + col;
        float v = acc[i][j][r] + badd;
        if (ACC) v += ((const float*)Cp)[idx];
        if (WB16) ((bf16*)Cp)[idx] = f2b(v);
        else      ((float*)Cp)[idx] = v;
      }
    }
  }
}

// ---- bidirectional encoder GRU: 64 blocks x 4 waves, 1 sync/step ----
// hb: [2 buf][2 dir][32][1024] bf16 (device-scope). fp32 master h in registers.
__global__ __launch_bounds__(256) void enc_loop_k(
  const float* __restrict__ gi_f, const float* __restrict__ gi_b,
  const bf16* __restrict__ whhf, const bf16* __restrict__ whhb,
  const float* __restrict__ bhhf, const float* __restrict__ bhhb,
  const float* __restrict__ enc_init,
  bf16* __restrict__ hb, bf16* __restrict__ enc_out, unsigned* __restrict__ bar)
{
  __shared__ bf16 hst[32][1032];
  const int tid = threadIdx.x, bid = blockIdx.x;
  const int w = tid>>6, l = tid&63;
  const int lr = l&15, koff = (l>>4)*8, rb = (l>>4)*4;
  const int dir = bid>>5;
  const int rest = (bid&31)*4 + w;           // 0..127
  const int mt = rest>>6, jt = rest&63;
  const int col = jt*16 + lr;
  const bf16* W    = dir ? whhb : whhf;
  const float* gi  = dir ? gi_b : gi_f;
  const float* bhh = dir ? bhhb : bhhf;
  const float br_ = bhh[col], bz_ = bhh[H_+col], bn_ = bhh[2*H_+col];
  float hreg[4];
  {
    float v = enc_init[dir*H_ + col];
    bf16 vb = f2b(v);
    #pragma unroll
    for (int ri=0; ri<4; ++ri){
      hreg[ri] = v;
      dsth(hb + dir*32768 + (mt*16 + rb + ri)*H_ + col, vb);  // buf 0
    }
  }
  gbar(bar, 0, bid, 8);
  for (int s = 0; s < 64; ++s){
    const int rbuf = s&1, wbuf = rbuf^1;
    // stage h (this dir) -> LDS, device-scope 8B loads
    {
      const bf16* src = hb + rbuf*65536 + dir*32768;
      #pragma unroll 8
      for (int c = 0; c < 32; ++c){
        int g = c*256 + tid;                 // 8192 chunks of 8B
        unsigned long long v = dld64(src + g*4);
        *(unsigned long long*)&hst[g>>8][(g&255)*4] = v;
      }
    }
    __syncthreads();
    f4 accr = (f4){0,0,0,0}, accz = (f4){0,0,0,0}, accn = (f4){0,0,0,0};
    const bf16* pa = &hst[mt*16 + lr][koff];
    const bf16* pr = W + (size_t)(jt*16 + lr)*H_ + koff;
    const bf16* pz = pr + (size_t)H_*H_;
    const bf16* pn = pz + (size_t)H_*H_;
    #pragma unroll 4
    for (int k0 = 0; k0 < H_; k0 += 32){
      s8v a = *(const s8v*)(pa + k0);
      accr = MFMA16(a, *(const s8v*)(pr + k0), accr);
      accz = MFMA16(a, *(const s8v*)(pz + k0), accz);
      accn = MFMA16(a, *(const s8v*)(pn + k0), accn);
    }
    const int es = dir ? (63 - s) : s;
    bf16* hbw = hb + wbuf*65536 + dir*32768;
    #pragma unroll
    for (int ri = 0; ri < 4; ++ri){
      const int b_ = mt*16 + rb + ri;
      const size_t gr = (size_t)(es*B_ + b_)*H3_;
      float ir = gi[gr + col], iz = gi[gr + H_ + col], inn = gi[gr + 2*H_ + col];
      float rg = fsigmoid(ir + accr[ri] + br_);
      float zg = fsigmoid(iz + accz[ri] + bz_);
      float ng = ftanh(inn + rg*(accn[ri] + bn_));
      float hnew = (1.f - zg)*ng + zg*hreg[ri];
      hreg[ri] = hnew;
      bf16 h16 = f2b(hnew);
      dsth(hbw + b_*H_ + col, h16);
      enc_out[(size_t)(es*B_ + b_)*2048 + dir*H_ + col] = h16;   // normal store, read post-kernel
    }
    gbar(bar, 1+s, bid, 8);
  }
}

// ---- decoder with attention: 128 blocks, 3 syncs/step ----
__global__ __launch_bounds__(256) void dec_loop_k(
  const float* __restrict__ gi_base,   // [2048][3072]
  const bf16* __restrict__ encW1b,     // [2048][1024] (read-only, cached)
  const bf16* __restrict__ encWgb,     // [2048][3072] (read-only, cached)
  const bf16* __restrict__ whhd,       // [3072][1024]
  const float* __restrict__ bhhd,
  const bf16* __restrict__ w1b,        // [1024][3072]
  const float* __restrict__ attnW2,    // [1024]
  const float* __restrict__ dinh,      // [1024]
  bf16* __restrict__ hdb,              // [32][1024] device-scope
  bf16* __restrict__ hW1b,             // [32][1024] device-scope
  float* __restrict__ gh,              // [32][3072] device-scope
  float* __restrict__ wat,             // [64][32]   device-scope
  bf16* __restrict__ h_all,            // [2048][1024] normal
  unsigned* __restrict__ bar)
{
  __shared__ union { bf16 hst[32][1032]; bf16 w1st[32768]; } u;
  __shared__ float watst[64];
  __shared__ float sc[32];
  const int tid = threadIdx.x, bid = blockIdx.x;
  const int tg = bid*256 + tid;        // (b, j)
  const int db = tg>>10, dj = tg&1023;
  float hreg = dinh[dj];
  dsth(hdb + tg, f2b(hreg));
  gbar(bar, 80, bid, 16);
  const int w = tid>>6, l = tid&63;
  const int lr = l&15, koff = (l>>4)*8, rbv = (l>>4)*4;
  // XCD-localized phase-A task map
  const int xcd = bid & 7;
  const int aslot = (bid>>3)*4 + w;     // 0..63
  int slot = 81;
  for (int t = 0; t < 64; ++t){
    // ---- stage h -> LDS (device-scope 8B loads)
    {
      #pragma unroll 8
      for (int c = 0; c < 32; ++c){
        int g = c*256 + tid;
        unsigned long long v = dld64(hdb + g*4);
        *(unsigned long long*)&u.hst[g>>8][(g&255)*4] = v;
      }
    }
    __syncthreads();
    // ---- phase A
    if (aslot < 48){                     // gh = h @ Whh^T + bhh : nt tile local to XCD
      const int nt = xcd*24 + (aslot>>1);
      const int mt = aslot&1;
      f4 acc = (f4){0,0,0,0};
      const bf16* pa = &u.hst[mt*16 + lr][koff];
      const bf16* pb = whhd + (size_t)(nt*16 + lr)*H_ + koff;
      #pragma unroll 4
      for (int k0=0;k0<H_;k0+=32)
        acc = MFMA16(*(const s8v*)(pa+k0), *(const s8v*)(pb+k0), acc);
      const int colA = nt*16 + lr;
      const float bv = bhhd[colA];
      #pragma unroll
      for (int ri=0;ri<4;++ri)
        dstf(gh + (mt*16 + rbv + ri)*H3_ + colA, acc[ri] + bv);
    } else {                             // hW1 = h @ W1h^T : jt tile local to XCD
      const int s2 = aslot - 48;
      const int jt = xcd*8 + (s2>>1);
      const int mt = s2&1;
      f4 acc = (f4){0,0,0,0};
      const bf16* pa = &u.hst[mt*16 + lr][koff];
      const bf16* pb = w1b + (size_t)(jt*16 + lr)*H3_ + 2048 + koff;
      #pragma unroll 4
      for (int k0 = 0; k0 < H_; k0 += 32)
        acc = MFMA16(*(const s8v*)(pa + k0), *(const s8v*)(pb + k0), acc);
      const int colA = jt*16 + lr;
      #pragma unroll
      for (int ri=0; ri<4; ++ri)
        dsth(hW1b + (mt*16 + rbv + ri)*H_ + colA, f2b(acc[ri]));
    }
    gbar(bar, slot++, bid, 16);
    // ---- phase B: scores + softmax over batch (block s < 64)
    if (bid < 64){
      // stage hW1 -> LDS with bank-spreading permutation slot16 = b*128 + ii*8 + part
      #pragma unroll 8
      for (int c = 0; c < 32; ++c){
        int g = c*256 + tid;               // 8B chunk id
        int b = g>>8, cc2 = g&255, cc = cc2>>1, half = cc2&1;
        int s16 = b*128 + (cc&15)*8 + (cc>>4);
        unsigned long long v = dld64(hW1b + g*4);
        *(unsigned long long*)&u.w1st[s16*8 + half*4] = v;
      }
      __syncthreads();
      const int s = bid;
      const int b_ = tid>>3, part = tid&7;
      const bf16* e  = encW1b + (size_t)(s*B_ + b_)*H_ + part*128;
      const float* w2p = attnW2 + part*128;
      float p = 0.f;
      #pragma unroll 2
      for (int ii=0; ii<16; ++ii){
        union { s8v v; unsigned short uu[8]; } ev, hv;
        ev.v = *(const s8v*)(e + ii*8);
        hv.v = *(const s8v*)&u.w1st[(b_*128 + ii*8 + part)*8];
        f4 wa  = *(const f4*)(w2p + ii*8);
        f4 wb2 = *(const f4*)(w2p + ii*8 + 4);
        #pragma unroll
        for (int k=0;k<8;k++){
          float x = bfu2f(ev.uu[k]) + bfu2f(hv.uu[k]);
          float th = ftanh(x);
          p += (k<4 ? wa[k] : wb2[k-4])*th;
        }
      }
      p += __shfl_xor(p,1); p += __shfl_xor(p,2); p += __shfl_xor(p,4);
      if (part == 0) sc[b_] = p;
      __syncthreads();
      if (tid < 32){
        float evx = __expf(sc[tid]);
        float ssum = evx;
        ssum += __shfl_xor(ssum,1);  ssum += __shfl_xor(ssum,2);
        ssum += __shfl_xor(ssum,4);  ssum += __shfl_xor(ssum,8);
        ssum += __shfl_xor(ssum,16);
        dstf(wat + s*B_ + tid, evx/ssum);
      }
    }
    gbar(bar, slot++, bid, 16);
    // ---- phase D: glimpse weighted sum + GRU pointwise (db constant per block)
    if (tid < 64) watst[tid] = dldf(wat + tid*B_ + db);
    __syncthreads();
    {
      float g0=0.f, g1=0.f, g2=0.f;
      #pragma unroll 4
      for (int s2=0;s2<64;++s2){
        float wv = watst[s2];
        const bf16* ro = encWgb + (size_t)(s2*B_ + db)*H3_ + dj;
        g0 += wv*b2f(ro[0]);
        g1 += wv*b2f(ro[H_]);
        g2 += wv*b2f(ro[2*H_]);
      }
      const size_t gr = (size_t)(t*B_ + db)*H3_;
      float ir  = gi_base[gr + dj] + g0;
      float iz  = gi_base[gr + H_ + dj] + g1;
      float inn = gi_base[gr + 2*H_ + dj] + g2;
      float hr_ = dldf(gh + db*H3_ + dj);
      float hz_ = dldf(gh + db*H3_ + H_ + dj);
      float hn_ = dldf(gh + db*H3_ + 2*H_ + dj);
      float rg = fsigmoid(ir + hr_);
      float zg = fsigmoid(iz + hz_);
      float ng = ftanh(inn + rg*hn_);
      float hnew = (1.f - zg)*ng + zg*hreg;
      hreg = hnew;
      bf16 h16 = f2b(hnew);
      dsth(hdb + db*H_ + dj, h16);
      h_all[(size_t)(t*B_ + db)*H_ + dj] = h16;   // normal store, read post-kernel
    }
    gbar(bar, slot++, bid, 16);
  }
}

// ---- 2-pass online row softmax over V (in place on d_out) ----
__global__ __launch_bounds__(256) void softmax_rows_k(float* __restrict__ out){
  __shared__ float wm[4], wl[4];
  const int tid = threadIdx.x;
  float* p = out + (size_t)blockIdx.x*V_;
  float m = -1e30f, lsum = 0.f;
  for (int j = tid; j < V_; j += 256){
    float v = p[j];
    float mn = fmaxf(m, v);
    lsum = lsum*__expf(m - mn) + __expf(v - mn);
    m = mn;
  }
  #pragma unroll
  for (int o = 32; o; o >>= 1){
    float mo = __shfl_xor(m, o), lo_ = __shfl_xor(lsum, o);
    float mn = fmaxf(m, mo);
    lsum = lsum*__expf(m - mn) + lo_*__expf(mo - mn);
    m = mn;
  }
  if ((tid&63)==0){ wm[tid>>6] = m; wl[tid>>6] = lsum; }
  __syncthreads();
  float M = fmaxf(fmaxf(wm[0],wm[1]), fmaxf(wm[2],wm[3]));
  float L = wl[0]*__expf(wm[0]-M) + wl[1]*__expf(wm[1]-M)
          + wl[2]*__expf(wm[2]-M) + wl[3]*__expf(wm[3]-M);
  float inv = 1.f/L;
  for (int j = tid; j < V_; j += 256) p[j] = __expf(p[j]-M)*inv;
}

extern "C" void kernel_launch(void* const* d_in, const int* in_sizes, int n_in,
                              void* d_out, int out_size, void* d_ws, size_t ws_size,
                              hipStream_t stream)
{
  (void)in_sizes; (void)n_in; (void)out_size; (void)ws_size;
  const int*   iseq  = (const int*)d_in[0];
  const int*   tseq  = (const int*)d_in[1];
  const float* emb   = (const float*)d_in[2];
  const float* wihf  = (const float*)d_in[3];
  const float* whhf_f= (const float*)d_in[4];
  const float* bihf  = (const float*)d_in[5];
  const float* bhhf  = (const float*)d_in[6];
  const float* wihb  = (const float*)d_in[7];
  const float* whhb_f= (const float*)d_in[8];
  const float* bihb  = (const float*)d_in[9];
  const float* bhhb  = (const float*)d_in[10];
  const float* einit = (const float*)d_in[11];
  const float* wihd  = (const float*)d_in[12];
  const float* whhd_f= (const float*)d_in[13];
  const float* bihd  = (const float*)d_in[14];
  const float* bhhd  = (const float*)d_in[15];
  const float* dinh  = (const float*)d_in[16];
  const float* dino  = (const float*)d_in[17];
  const float* w1    = (const float*)d_in[18];
  const float* w2    = (const float*)d_in[19];
  const float* outw  = (const float*)d_in[20];
  const float* outb  = (const float*)d_in[21];
  float* out = (float*)d_out;

  char* ws = (char*)d_ws;
  size_t off = 0;
  auto alloc = [&](size_t bytes)->char*{ char* p = ws + off; off += (bytes + 255) & ~(size_t)255; return p; };
  const size_t bar_bytes = (size_t)273*SLOT_U*4;
  unsigned* bar  = (unsigned*)alloc(bar_bytes);
  bf16* x_b      = (bf16*)alloc((size_t)2048*512*2);
  bf16* lo_b     = (bf16*)alloc((size_t)2048*512*2);
  bf16* wihf_b   = (bf16*)alloc((size_t)3072*512*2);
  bf16* wihb_b   = (bf16*)alloc((size_t)3072*512*2);
  bf16* whhf_b   = (bf16*)alloc((size_t)3072*1024*2);
  bf16* whhb_b   = (bf16*)alloc((size_t)3072*1024*2);
  bf16* wihd_b   = (bf16*)alloc((size_t)3072*3072*2);
  bf16* whhd_b   = (bf16*)alloc((size_t)3072*1024*2);
  bf16* w1_b     = (bf16*)alloc((size_t)1024*3072*2);
  bf16* outw_b   = (bf16*)alloc((size_t)32000*1024*2);
  float* gi_f    = (float*)alloc((size_t)2048*3072*4);
  float* gi_b    = (float*)alloc((size_t)2048*3072*4);
  float* gi_d    = (float*)alloc((size_t)2048*3072*4);
  bf16* enc_b    = (bf16*)alloc((size_t)2048*2048*2);
  bf16* encW1_b  = (bf16*)alloc((size_t)2048*1024*2);
  bf16* encWg_b  = (bf16*)alloc((size_t)2048*3072*2);
  bf16*  henc_b  = (bf16*)alloc((size_t)2*65536*2);
  bf16*  hdb     = (bf16*)alloc((size_t)32768*2);
  bf16*  hW1b    = (bf16*)alloc((size_t)32768*2);
  float* ghb     = (float*)alloc((size_t)32*3072*4);
  float* wat     = (float*)alloc((size_t)64*32*4);
  bf16*  hall_b  = (bf16*)alloc((size_t)2048*1024*2);

  hipMemsetAsync(bar, 0, bar_bytes, stream);

  auto cgrid = [](int n8){ int g = (n8 + 255)/256; return g > 2048 ? 2048 : g; };
  gather_x_k <<<512, 256, 0, stream>>>(emb, iseq, x_b);
  gather_lo_k<<<512, 256, 0, stream>>>(emb, tseq, dino, lo_b);
  cast_bf16_k<<<cgrid(196608),  256, 0, stream>>>(wihf,   wihf_b, 196608);
  cast_bf16_k<<<cgrid(196608),  256, 0, stream>>>(wihb,   wihb_b, 196608);
  cast_bf16_k<<<cgrid(393216),  256, 0, stream>>>(whhf_f, whhf_b, 393216);
  cast_bf16_k<<<cgrid(393216),  256, 0, stream>>>(whhb_f, whhb_b, 393216);
  cast_bf16_k<<<cgrid(1179648), 256, 0, stream>>>(wihd,   wihd_b, 1179648);
  cast_bf16_k<<<cgrid(393216),  256, 0, stream>>>(whhd_f, whhd_b, 393216);
  cast_bf16_k<<<cgrid(393216),  256, 0, stream>>>(w1,     w1_b,   393216);
  cast_bf16_k<<<cgrid(4096000), 256, 0, stream>>>(outw,   outw_b, 4096000);

  // batched gi precomputes
  gemm_bt<0,0><<<dim3(24,16), 256, 0, stream>>>(x_b, 512, wihf_b,      512,  bihf,    gi_f, 3072, 512);
  gemm_bt<0,0><<<dim3(24,16), 256, 0, stream>>>(x_b, 512, wihb_b,      512,  bihb,    gi_b, 3072, 512);
  gemm_bt<0,0><<<dim3(24,16), 256, 0, stream>>>(x_b, 512, wihd_b,      3072, bihd,    gi_d, 3072, 512);
  gemm_bt<0,1><<<dim3(24,16), 256, 0, stream>>>(lo_b,512, wihd_b+2560, 3072, nullptr, gi_d, 3072, 512);

  enc_loop_k<<<64, 256, 0, stream>>>(gi_f, gi_b, whhf_b, whhb_b, bhhf, bhhb, einit,
                                     henc_b, enc_b, bar);

  // loop-invariant attention precomputes
  gemm_bt<1,0><<<dim3(8,16),  256, 0, stream>>>(enc_b, 2048, w1_b,       3072, nullptr, encW1_b, 1024, 2048);
  gemm_bt<1,0><<<dim3(24,16), 256, 0, stream>>>(enc_b, 2048, wihd_b+512, 3072, nullptr, encWg_b, 3072, 2048);

  dec_loop_k<<<128, 256, 0, stream>>>(gi_d, encW1_b, encWg_b, whhd_b, bhhd, w1_b, w2, dinh,
                                      hdb, hW1b, ghb, wat, hall_b, bar);

  // batched output projection + softmax
  gemm_bt<0,0><<<dim3(250,16), 256, 0, stream>>>(hall_b, 1024, outw_b, 1024, outb, out, 32000, 1024);
  softmax_rows_k<<<2048, 256, 0, stream>>>(out);
}